// Round 1
// baseline (369.819 us; speedup 1.0000x reference)
//
#include <hip/hip_runtime.h>

#define SS 2048
#define DD 64
#define QB 128      // q rows per block (4 waves x 32)
#define KVB 64      // kv rows per staged tile

typedef __attribute__((ext_vector_type(4)))  float f32x4;
typedef __attribute__((ext_vector_type(16))) float f32x16;
typedef __attribute__((ext_vector_type(8)))  short bf16x8;
typedef __attribute__((ext_vector_type(2)))  unsigned int u32x2;

static __device__ __forceinline__ unsigned short f2bf(float f) {
    unsigned u = __builtin_bit_cast(unsigned, f);
    u += 0x7FFFu + ((u >> 16) & 1u);
    return (unsigned short)(u >> 16);
}

static __device__ __forceinline__ f32x16 zero16() {
    f32x16 z;
#pragma unroll
    for (int i = 0; i < 16; ++i) z[i] = 0.f;
    return z;
}

union PFrag { bf16x8 v; unsigned w[4]; };

__global__ __launch_bounds__(256, 2)
void attn_fused(const float* __restrict__ gQ, const float* __restrict__ gK,
                const float* __restrict__ gV, float* __restrict__ gO,
                float* __restrict__ gP)
{
    __shared__ unsigned short Qs[QB * DD];   // [q][d] bf16 (scale+log2e folded), plain
    __shared__ unsigned short Ks[KVB * DD];  // [kv][d] bf16, 16B-chunk XOR swizzle
    __shared__ unsigned short Vt[DD * KVB];  // [d][kv] bf16 (transposed), swizzled

    const int tid  = threadIdx.x;
    const int lane = tid & 63;
    const int wave = tid >> 6;
    const int lo5  = lane & 31;
    const int hi   = lane >> 5;

    const int head = blockIdx.x >> 4;   // 0..31  (= b*16 + h)
    const int qblk = blockIdx.x & 15;
    const int q0b  = qblk * QB;

    const float* Qh = gQ + (size_t)head * SS * DD;
    const float* Kh = gK + (size_t)head * SS * DD;
    const float* Vh = gV + (size_t)head * SS * DD;
    float* Oh = gO + (size_t)head * SS * DD;
    float* Ph = gP + (size_t)head * SS * SS;

    const float SCALE = 0.125f * 1.44269504088896340736f; // (1/sqrt(64)) * log2(e)

    // ---- stage Q as scaled bf16 ----
#pragma unroll
    for (int it = 0; it < 8; ++it) {
        int m = it * 256 + tid;            // 2048 float4 units = 128q x 16
        int q = m >> 4, d4 = m & 15;
        f32x4 v = *(const f32x4*)(Qh + (size_t)(q0b + q) * DD + d4 * 4);
        unsigned a = (unsigned)f2bf(v.x * SCALE) | ((unsigned)f2bf(v.y * SCALE) << 16);
        unsigned b = (unsigned)f2bf(v.z * SCALE) | ((unsigned)f2bf(v.w * SCALE) << 16);
        u32x2 w; w.x = a; w.y = b;
        *(u32x2*)(Qs + q * 64 + d4 * 4) = w;
    }
    __syncthreads();

    // ---- Q B-fragments: B = Q^T[16d][32q]; lane: col q=lo5, k d = ks*16 + hi*8 + i ----
    const int qrow = wave * 32 + lo5;
    bf16x8 qf[4];
#pragma unroll
    for (int ks = 0; ks < 4; ++ks)
        qf[ks] = *(const bf16x8*)(Qs + qrow * 64 + ks * 16 + hi * 8);

    auto stageK = [&](int kv0) {
#pragma unroll
        for (int it = 0; it < 4; ++it) {
            int m = it * 256 + tid;        // 1024 float4 units = 64kv x 16
            int kv = m >> 4, d4 = m & 15;
            f32x4 v = *(const f32x4*)(Kh + (size_t)(kv0 + kv) * DD + d4 * 4);
            unsigned a = (unsigned)f2bf(v.x) | ((unsigned)f2bf(v.y) << 16);
            unsigned b = (unsigned)f2bf(v.z) | ((unsigned)f2bf(v.w) << 16);
            int c16 = (d4 >> 1) ^ (kv & 7);
            u32x2 w; w.x = a; w.y = b;
            *(u32x2*)(Ks + kv * 64 + c16 * 8 + (d4 & 1) * 4) = w;
        }
    };
    auto stageV = [&](int kv0) {
#pragma unroll
        for (int it = 0; it < 2; ++it) {
            int m = it * 256 + tid;        // 512 units = 32 kv-pairs x 16
            int kv2 = m >> 4, d4 = m & 15;
            const float* p0 = Vh + (size_t)(kv0 + kv2 * 2) * DD + d4 * 4;
            f32x4 v0 = *(const f32x4*)(p0);
            f32x4 v1 = *(const f32x4*)(p0 + DD);
#pragma unroll
            for (int c = 0; c < 4; ++c) {
                int d = d4 * 4 + c;
                unsigned u = (unsigned)f2bf(v0[c]) | ((unsigned)f2bf(v1[c]) << 16);
                int c16 = (kv2 >> 2) ^ (d & 7);
                *(unsigned*)(Vt + d * 64 + c16 * 8 + (kv2 & 3) * 2) = u;
            }
        }
    };

    // ================= PASS A: running max / denom only =================
    float m_run = -1e30f, l_run = 0.f;
    for (int kv0 = 0; kv0 < SS; kv0 += KVB) {
        __syncthreads();
        stageK(kv0);
        __syncthreads();
#pragma unroll
        for (int sub = 0; sub < 2; ++sub) {
            f32x16 acc = zero16();
            int kvl = sub * 32 + lo5;
#pragma unroll
            for (int ks = 0; ks < 4; ++ks) {
                bf16x8 kf = *(const bf16x8*)(Ks + kvl * 64 + ((((ks * 2) + hi) ^ (kvl & 7)) << 3));
                acc = __builtin_amdgcn_mfma_f32_32x32x16_bf16(kf, qf[ks], acc, 0, 0, 0);
            }
            float tm = acc[0];
#pragma unroll
            for (int r = 1; r < 16; ++r) tm = fmaxf(tm, acc[r]);
            float mn = fmaxf(m_run, tm);
            float sum = 0.f;
#pragma unroll
            for (int r = 0; r < 16; ++r) sum += __builtin_exp2f(acc[r] - mn);
            l_run = l_run * __builtin_exp2f(m_run - mn) + sum;
            m_run = mn;
        }
    }
    // combine lane vs lane^32 (same q, disjoint kv halves)
    {
        float mo = __shfl_xor(m_run, 32);
        float mf = fmaxf(m_run, mo);
        float la = l_run * __builtin_exp2f(m_run - mf);
        float lb = __shfl_xor(la, 32);
        l_run = la + lb;
        m_run = mf;
    }
    const float rinv = 1.0f / l_run;

    // ================= PASS B: recompute scores, write P, PV =================
    f32x16 o0 = zero16(), o1 = zero16();
    const int qg = q0b + wave * 32 + lo5;
    float* prow_base = Ph + (size_t)qg * SS;

    for (int kv0 = 0; kv0 < SS; kv0 += KVB) {
        __syncthreads();
        stageK(kv0);
        stageV(kv0);
        __syncthreads();
#pragma unroll
        for (int sub = 0; sub < 2; ++sub) {
            f32x16 acc = zero16();
            int kvl = sub * 32 + lo5;
#pragma unroll
            for (int ks = 0; ks < 4; ++ks) {
                bf16x8 kf = *(const bf16x8*)(Ks + kvl * 64 + ((((ks * 2) + hi) ^ (kvl & 7)) << 3));
                acc = __builtin_amdgcn_mfma_f32_32x32x16_bf16(kf, qf[ks], acc, 0, 0, 0);
            }
            float pr[16];
#pragma unroll
            for (int r = 0; r < 16; ++r) pr[r] = __builtin_exp2f(acc[r] - m_run);

            // store P (fp32, normalized): reg 4g+j -> kv_local = 8g + 4hi + j
            float* prow = prow_base + kv0 + sub * 32;
#pragma unroll
            for (int g = 0; g < 4; ++g) {
                f32x4 st = { pr[4*g+0] * rinv, pr[4*g+1] * rinv, pr[4*g+2] * rinv, pr[4*g+3] * rinv };
                *(f32x4*)(prow + g * 8 + hi * 4) = st;
            }

            // pack unnormalized p' to bf16 pairs
            unsigned u[8];
#pragma unroll
            for (int j = 0; j < 8; ++j)
                u[j] = (unsigned)f2bf(pr[2*j]) | ((unsigned)f2bf(pr[2*j+1]) << 16);

            // assemble P^T B-frags (col q = lo5, k kv = hi*8+i) via half-wave exchange
            unsigned s0 = __shfl_xor(u[0], 32), s1 = __shfl_xor(u[1], 32);
            unsigned s2 = __shfl_xor(u[2], 32), s3 = __shfl_xor(u[3], 32);
            unsigned s4 = __shfl_xor(u[4], 32), s5 = __shfl_xor(u[5], 32);
            unsigned s6 = __shfl_xor(u[6], 32), s7 = __shfl_xor(u[7], 32);
            PFrag pf0, pf1;
            pf0.w[0] = hi ? s2 : u[0];  pf0.w[1] = hi ? s3 : u[1];
            pf0.w[2] = hi ? u[2] : s0;  pf0.w[3] = hi ? u[3] : s1;
            pf1.w[0] = hi ? s6 : u[4];  pf1.w[1] = hi ? s7 : u[5];
            pf1.w[2] = hi ? u[6] : s4;  pf1.w[3] = hi ? u[7] : s5;

            // PV: O^T[64d][32q] += V^T * P^T ; A-frag from Vt
#pragma unroll
            for (int dt = 0; dt < 2; ++dt) {
                int drow = dt * 32 + lo5;
                int c0 = ((sub * 4) + 0 + hi) ^ (drow & 7);
                int c1 = ((sub * 4) + 2 + hi) ^ (drow & 7);
                bf16x8 vf0 = *(const bf16x8*)(Vt + drow * 64 + (c0 << 3));
                bf16x8 vf1 = *(const bf16x8*)(Vt + drow * 64 + (c1 << 3));
                f32x16& od = dt ? o1 : o0;
                od = __builtin_amdgcn_mfma_f32_32x32x16_bf16(vf0, pf0.v, od, 0, 0, 0);
                od = __builtin_amdgcn_mfma_f32_32x32x16_bf16(vf1, pf1.v, od, 0, 0, 0);
            }
        }
    }

    // ---- store O: O^T acc -> reg 4g+j of tile dt is d = dt*32 + 8g + 4hi + j ----
    float* orow = Oh + (size_t)qg * DD;
#pragma unroll
    for (int dt = 0; dt < 2; ++dt) {
        const f32x16& od = dt ? o1 : o0;
#pragma unroll
        for (int g = 0; g < 4; ++g) {
            f32x4 st = { od[4*g+0] * rinv, od[4*g+1] * rinv, od[4*g+2] * rinv, od[4*g+3] * rinv };
            *(f32x4*)(orow + dt * 32 + g * 8 + hi * 4) = st;
        }
    }
}

extern "C" void kernel_launch(void* const* d_in, const int* in_sizes, int n_in,
                              void* d_out, int out_size, void* d_ws, size_t ws_size,
                              hipStream_t stream) {
    const float* Q = (const float*)d_in[0];
    const float* K = (const float*)d_in[1];
    const float* V = (const float*)d_in[2];
    float* O = (float*)d_out;
    float* P = O + (size_t)2 * 16 * 2048 * 64;   // p_attn follows output
    hipLaunchKernelGGL(attn_fused, dim3(512), dim3(256), 0, stream, Q, K, V, O, P);
}

// Round 2
// 215.176 us; speedup vs baseline: 1.7187x; 1.7187x over previous
//
#include <hip/hip_runtime.h>

#define SS 2048
#define DD 64
#define QB 128      // q rows per block (4 waves x 32)
#define KVB 64      // kv rows per staged tile
#define NT (SS / KVB)

typedef unsigned short ushort_t;
typedef __attribute__((ext_vector_type(4)))  float f32x4;
typedef __attribute__((ext_vector_type(16))) float f32x16;
typedef __attribute__((ext_vector_type(8)))  short bf16x8;
typedef __attribute__((ext_vector_type(2)))  unsigned int u32x2;

static __device__ __forceinline__ unsigned short f2bf(float f) {
    unsigned u = __builtin_bit_cast(unsigned, f);
    u += 0x7FFFu + ((u >> 16) & 1u);
    return (unsigned short)(u >> 16);
}

static __device__ __forceinline__ f32x16 zero16() {
    f32x16 z;
#pragma unroll
    for (int i = 0; i < 16; ++i) z[i] = 0.f;
    return z;
}

union PFrag { bf16x8 v; unsigned w[4]; };

#define GLL16(src, dst) \
    __builtin_amdgcn_global_load_lds((const __attribute__((address_space(1))) void*)(src), \
                                     (__attribute__((address_space(3))) void*)(dst), 16, 0, 0)

// ---------------- prologue: fp32 -> bf16 (optionally scaled) ----------------
__global__ void cvt_bf16(const float* __restrict__ src, ushort_t* __restrict__ dst,
                         int n8, float scale)
{
    int i = blockIdx.x * blockDim.x + threadIdx.x;
    if (i >= n8) return;
    f32x4 a = ((const f32x4*)src)[2 * i];
    f32x4 b = ((const f32x4*)src)[2 * i + 1];
    bf16x8 o;
#pragma unroll
    for (int j = 0; j < 4; ++j) o[j] = (short)f2bf(a[j] * scale);
#pragma unroll
    for (int j = 0; j < 4; ++j) o[4 + j] = (short)f2bf(b[j] * scale);
    ((bf16x8*)dst)[i] = o;
}

// ---------------- prologue: V [h][kv][d] fp32 -> V^T [h][d][kv] bf16 ----------------
__global__ void transposeV(const float* __restrict__ V, ushort_t* __restrict__ Vt)
{
    __shared__ float tile[64][65];
    const int tid = threadIdx.x;
    const int hh = blockIdx.x >> 5;    // 0..31
    const int kt = blockIdx.x & 31;    // kv tile

#pragma unroll
    for (int it = 0; it < 4; ++it) {
        int m = it * 256 + tid;        // 1024 units = 64 rows x 16 f32x4
        int r = m >> 4, c4 = m & 15;
        f32x4 v = *(const f32x4*)(V + ((size_t)(hh * SS + kt * 64 + r)) * DD + c4 * 4);
#pragma unroll
        for (int j = 0; j < 4; ++j) tile[r][c4 * 4 + j] = v[j];
    }
    __syncthreads();
#pragma unroll
    for (int it = 0; it < 2; ++it) {
        int m = it * 256 + tid;        // 512 units = 64 d-rows x 8 chunks
        int d = m >> 3, c8 = m & 7;
        bf16x8 o;
#pragma unroll
        for (int j = 0; j < 8; ++j) o[j] = (short)f2bf(tile[c8 * 8 + j][d]);
        *(bf16x8*)(Vt + ((size_t)hh * DD + d) * SS + kt * 64 + c8 * 8) = o;
    }
}

// ---------------- main fused attention ----------------
__global__ __launch_bounds__(256, 2)
void attn_main(const ushort_t* __restrict__ Qbf, const ushort_t* __restrict__ Kbf,
               const ushort_t* __restrict__ Vtbf, float* __restrict__ gO,
               float* __restrict__ gP)
{
    // per buffer: [0..4095] K tile [kv][d] (chunk-swizzled), [4096..8191] Vt tile [d][kv]
    __shared__ ushort_t lds[2][8192];

    const int tid  = threadIdx.x;
    const int lane = tid & 63;
    const int wave = tid >> 6;
    const int lo5  = lane & 31;
    const int hi   = lane >> 5;

    const int bid  = blockIdx.x;
    const int wg   = (bid & 7) * 64 + (bid >> 3);   // XCD-contiguous: 64 blocks (4 heads) per XCD
    const int head = wg >> 4;
    const int q0b  = (wg & 15) * QB;

    const ushort_t* Qh = Qbf  + (size_t)head * SS * DD;
    const ushort_t* Kh = Kbf  + (size_t)head * SS * DD;
    const ushort_t* Vh = Vtbf + (size_t)head * DD * SS;   // [d][kv]
    float* Oh = gO + (size_t)head * SS * DD;
    float* Ph = gP + (size_t)head * SS * SS;

    // ---- Q B-fragments straight from global bf16 (scale+log2e folded) ----
    const int qg = q0b + wave * 32 + lo5;
    bf16x8 qf[4];
#pragma unroll
    for (int ks = 0; ks < 4; ++ks)
        qf[ks] = *(const bf16x8*)(Qh + (size_t)qg * DD + ks * 16 + hi * 8);

    // ---- staging source addresses (pre-swizzled so LDS can stay linear-dest) ----
    const int lgrp = lane >> 3;              // 0..7
    const int lchk = (lane & 7) ^ lgrp;      // logical 16B chunk (involution swizzle)
    const ushort_t* srcK[2], *srcV[2];
    ushort_t* dK[2][2], *dV[2][2];
#pragma unroll
    for (int j = 0; j < 2; ++j) {
        int W = wave * 2 + j;                // 0..7
        srcK[j] = Kh + (size_t)(W * 8 + lgrp) * DD + lchk * 8;
        srcV[j] = Vh + (size_t)(W * 8 + lgrp) * SS + lchk * 8;
#pragma unroll
        for (int b = 0; b < 2; ++b) {
            dK[b][j] = &lds[b][W * 512];
            dV[b][j] = &lds[b][4096 + W * 512];
        }
    }

    // ================= PASS A: denominator only (max-free; scores are O(1)) =================
    // stage K tile 0
#pragma unroll
    for (int j = 0; j < 2; ++j) GLL16(srcK[j], dK[0][j]);
    __syncthreads();

    float lsum0 = 0.f, lsum1 = 0.f;
    int buf = 0;
    for (int t = 0; t < NT; ++t) {
        if (t + 1 < NT) {
#pragma unroll
            for (int j = 0; j < 2; ++j)
                GLL16(srcK[j] + (size_t)(t + 1) * KVB * DD, dK[buf ^ 1][j]);
        }
        const ushort_t* Ksb = &lds[buf][0];
#pragma unroll
        for (int sub = 0; sub < 2; ++sub) {
            f32x16 acc = zero16();
            int kvl = sub * 32 + lo5;
#pragma unroll
            for (int ks = 0; ks < 4; ++ks) {
                bf16x8 kf = *(const bf16x8*)(Ksb + kvl * 64 + ((((ks * 2) + hi) ^ (kvl & 7)) << 3));
                acc = __builtin_amdgcn_mfma_f32_32x32x16_bf16(kf, qf[ks], acc, 0, 0, 0);
            }
#pragma unroll
            for (int r = 0; r < 16; r += 2) {
                lsum0 += __builtin_exp2f(acc[r]);
                lsum1 += __builtin_exp2f(acc[r + 1]);
            }
        }
        __syncthreads();
        buf ^= 1;
    }
    float l_run = lsum0 + lsum1;
    l_run += __shfl_xor(l_run, 32);          // combine the two kv halves (same q)
    const float rinv = 1.0f / l_run;

    // ================= PASS B: recompute scores, write P, PV =================
    f32x16 o0 = zero16(), o1 = zero16();
    float* prow_base = Ph + (size_t)qg * SS;

    // stage K+V tile 0 into buffer 0
#pragma unroll
    for (int j = 0; j < 2; ++j) { GLL16(srcK[j], dK[0][j]); GLL16(srcV[j], dV[0][j]); }
    __syncthreads();

    buf = 0;
    for (int t = 0; t < NT; ++t) {
        if (t + 1 < NT) {
#pragma unroll
            for (int j = 0; j < 2; ++j) {
                GLL16(srcK[j] + (size_t)(t + 1) * KVB * DD, dK[buf ^ 1][j]);
                GLL16(srcV[j] + (size_t)(t + 1) * KVB,      dV[buf ^ 1][j]);
            }
        }
        const ushort_t* Ksb = &lds[buf][0];
        const ushort_t* Vtb = &lds[buf][4096];
#pragma unroll
        for (int sub = 0; sub < 2; ++sub) {
            f32x16 acc = zero16();
            int kvl = sub * 32 + lo5;
#pragma unroll
            for (int ks = 0; ks < 4; ++ks) {
                bf16x8 kf = *(const bf16x8*)(Ksb + kvl * 64 + ((((ks * 2) + hi) ^ (kvl & 7)) << 3));
                acc = __builtin_amdgcn_mfma_f32_32x32x16_bf16(kf, qf[ks], acc, 0, 0, 0);
            }
            float pr[16];
#pragma unroll
            for (int r = 0; r < 16; ++r) pr[r] = __builtin_exp2f(acc[r]);

            // store P (fp32, normalized): reg 4g+j -> kv_local = 8g + 4hi + j
            float* prow = prow_base + t * KVB + sub * 32;
#pragma unroll
            for (int g = 0; g < 4; ++g) {
                f32x4 st = { pr[4*g+0] * rinv, pr[4*g+1] * rinv, pr[4*g+2] * rinv, pr[4*g+3] * rinv };
                *(f32x4*)(prow + g * 8 + hi * 4) = st;
            }

            // pack unnormalized p to bf16 pairs
            unsigned u[8];
#pragma unroll
            for (int j = 0; j < 8; ++j)
                u[j] = (unsigned)f2bf(pr[2*j]) | ((unsigned)f2bf(pr[2*j+1]) << 16);

            // assemble P^T B-frags (col q = lo5, k kv = hi*8+i) via half-wave exchange
            unsigned s0 = __shfl_xor(u[0], 32), s1 = __shfl_xor(u[1], 32);
            unsigned s2 = __shfl_xor(u[2], 32), s3 = __shfl_xor(u[3], 32);
            unsigned s4 = __shfl_xor(u[4], 32), s5 = __shfl_xor(u[5], 32);
            unsigned s6 = __shfl_xor(u[6], 32), s7 = __shfl_xor(u[7], 32);
            PFrag pf0, pf1;
            pf0.w[0] = hi ? s2 : u[0];  pf0.w[1] = hi ? s3 : u[1];
            pf0.w[2] = hi ? u[2] : s0;  pf0.w[3] = hi ? u[3] : s1;
            pf1.w[0] = hi ? s6 : u[4];  pf1.w[1] = hi ? s7 : u[5];
            pf1.w[2] = hi ? u[6] : s4;  pf1.w[3] = hi ? u[7] : s5;

            // PV: O^T[64d][32q] += V^T * P^T
#pragma unroll
            for (int dt = 0; dt < 2; ++dt) {
                int drow = dt * 32 + lo5;
                int c0 = ((sub * 4) + 0 + hi) ^ (drow & 7);
                int c1 = ((sub * 4) + 2 + hi) ^ (drow & 7);
                bf16x8 vf0 = *(const bf16x8*)(Vtb + drow * 64 + (c0 << 3));
                bf16x8 vf1 = *(const bf16x8*)(Vtb + drow * 64 + (c1 << 3));
                f32x16& od = dt ? o1 : o0;
                od = __builtin_amdgcn_mfma_f32_32x32x16_bf16(vf0, pf0.v, od, 0, 0, 0);
                od = __builtin_amdgcn_mfma_f32_32x32x16_bf16(vf1, pf1.v, od, 0, 0, 0);
            }
        }
        __syncthreads();
        buf ^= 1;
    }

    // ---- store O: O^T acc -> reg 4g+j of tile dt is d = dt*32 + 8g + 4hi + j ----
    float* orow = Oh + (size_t)qg * DD;
#pragma unroll
    for (int dt = 0; dt < 2; ++dt) {
        const f32x16& od = dt ? o1 : o0;
#pragma unroll
        for (int g = 0; g < 4; ++g) {
            f32x4 st = { od[4*g+0] * rinv, od[4*g+1] * rinv, od[4*g+2] * rinv, od[4*g+3] * rinv };
            *(f32x4*)(orow + dt * 32 + g * 8 + hi * 4) = st;
        }
    }
}

// ================= fallback (round-1 kernel) if ws too small =================
__global__ __launch_bounds__(256, 2)
void attn_fused(const float* __restrict__ gQ, const float* __restrict__ gK,
                const float* __restrict__ gV, float* __restrict__ gO,
                float* __restrict__ gP)
{
    __shared__ unsigned short Qs[QB * DD];
    __shared__ unsigned short Ks[KVB * DD];
    __shared__ unsigned short Vt[DD * KVB];

    const int tid  = threadIdx.x;
    const int lane = tid & 63;
    const int wave = tid >> 6;
    const int lo5  = lane & 31;
    const int hi   = lane >> 5;

    const int head = blockIdx.x >> 4;
    const int qblk = blockIdx.x & 15;
    const int q0b  = qblk * QB;

    const float* Qh = gQ + (size_t)head * SS * DD;
    const float* Kh = gK + (size_t)head * SS * DD;
    const float* Vh = gV + (size_t)head * SS * DD;
    float* Oh = gO + (size_t)head * SS * DD;
    float* Ph = gP + (size_t)head * SS * SS;

    const float SCALE = 0.125f * 1.44269504088896340736f;

#pragma unroll
    for (int it = 0; it < 8; ++it) {
        int m = it * 256 + tid;
        int q = m >> 4, d4 = m & 15;
        f32x4 v = *(const f32x4*)(Qh + (size_t)(q0b + q) * DD + d4 * 4);
        unsigned a = (unsigned)f2bf(v.x * SCALE) | ((unsigned)f2bf(v.y * SCALE) << 16);
        unsigned b = (unsigned)f2bf(v.z * SCALE) | ((unsigned)f2bf(v.w * SCALE) << 16);
        u32x2 w; w.x = a; w.y = b;
        *(u32x2*)(Qs + q * 64 + d4 * 4) = w;
    }
    __syncthreads();

    const int qrow = wave * 32 + lo5;
    bf16x8 qf[4];
#pragma unroll
    for (int ks = 0; ks < 4; ++ks)
        qf[ks] = *(const bf16x8*)(Qs + qrow * 64 + ks * 16 + hi * 8);

    auto stageK = [&](int kv0) {
#pragma unroll
        for (int it = 0; it < 4; ++it) {
            int m = it * 256 + tid;
            int kv = m >> 4, d4 = m & 15;
            f32x4 v = *(const f32x4*)(Kh + (size_t)(kv0 + kv) * DD + d4 * 4);
            unsigned a = (unsigned)f2bf(v.x) | ((unsigned)f2bf(v.y) << 16);
            unsigned b = (unsigned)f2bf(v.z) | ((unsigned)f2bf(v.w) << 16);
            int c16 = (d4 >> 1) ^ (kv & 7);
            u32x2 w; w.x = a; w.y = b;
            *(u32x2*)(Ks + kv * 64 + c16 * 8 + (d4 & 1) * 4) = w;
        }
    };
    auto stageV = [&](int kv0) {
#pragma unroll
        for (int it = 0; it < 2; ++it) {
            int m = it * 256 + tid;
            int kv2 = m >> 4, d4 = m & 15;
            const float* p0 = Vh + (size_t)(kv0 + kv2 * 2) * DD + d4 * 4;
            f32x4 v0 = *(const f32x4*)(p0);
            f32x4 v1 = *(const f32x4*)(p0 + DD);
#pragma unroll
            for (int c = 0; c < 4; ++c) {
                int d = d4 * 4 + c;
                unsigned u = (unsigned)f2bf(v0[c]) | ((unsigned)f2bf(v1[c]) << 16);
                int c16 = (kv2 >> 2) ^ (d & 7);
                *(unsigned*)(Vt + d * 64 + c16 * 8 + (kv2 & 3) * 2) = u;
            }
        }
    };

    float m_run = -1e30f, l_run = 0.f;
    for (int kv0 = 0; kv0 < SS; kv0 += KVB) {
        __syncthreads();
        stageK(kv0);
        __syncthreads();
#pragma unroll
        for (int sub = 0; sub < 2; ++sub) {
            f32x16 acc = zero16();
            int kvl = sub * 32 + lo5;
#pragma unroll
            for (int ks = 0; ks < 4; ++ks) {
                bf16x8 kf = *(const bf16x8*)(Ks + kvl * 64 + ((((ks * 2) + hi) ^ (kvl & 7)) << 3));
                acc = __builtin_amdgcn_mfma_f32_32x32x16_bf16(kf, qf[ks], acc, 0, 0, 0);
            }
            float tm = acc[0];
#pragma unroll
            for (int r = 1; r < 16; ++r) tm = fmaxf(tm, acc[r]);
            float mn = fmaxf(m_run, tm);
            float sum = 0.f;
#pragma unroll
            for (int r = 0; r < 16; ++r) sum += __builtin_exp2f(acc[r] - mn);
            l_run = l_run * __builtin_exp2f(m_run - mn) + sum;
            m_run = mn;
        }
    }
    {
        float mo = __shfl_xor(m_run, 32);
        float mf = fmaxf(m_run, mo);
        float la = l_run * __builtin_exp2f(m_run - mf);
        float lb = __shfl_xor(la, 32);
        l_run = la + lb;
        m_run = mf;
    }
    const float rinv = 1.0f / l_run;

    f32x16 o0 = zero16(), o1 = zero16();
    const int qg = q0b + wave * 32 + lo5;
    float* prow_base = Ph + (size_t)qg * SS;

    for (int kv0 = 0; kv0 < SS; kv0 += KVB) {
        __syncthreads();
        stageK(kv0);
        stageV(kv0);
        __syncthreads();
#pragma unroll
        for (int sub = 0; sub < 2; ++sub) {
            f32x16 acc = zero16();
            int kvl = sub * 32 + lo5;
#pragma unroll
            for (int ks = 0; ks < 4; ++ks) {
                bf16x8 kf = *(const bf16x8*)(Ks + kvl * 64 + ((((ks * 2) + hi) ^ (kvl & 7)) << 3));
                acc = __builtin_amdgcn_mfma_f32_32x32x16_bf16(kf, qf[ks], acc, 0, 0, 0);
            }
            float pr[16];
#pragma unroll
            for (int r = 0; r < 16; ++r) pr[r] = __builtin_exp2f(acc[r] - m_run);

            float* prow = prow_base + kv0 + sub * 32;
#pragma unroll
            for (int g = 0; g < 4; ++g) {
                f32x4 st = { pr[4*g+0] * rinv, pr[4*g+1] * rinv, pr[4*g+2] * rinv, pr[4*g+3] * rinv };
                *(f32x4*)(prow + g * 8 + hi * 4) = st;
            }

            unsigned u[8];
#pragma unroll
            for (int j = 0; j < 8; ++j)
                u[j] = (unsigned)f2bf(pr[2*j]) | ((unsigned)f2bf(pr[2*j+1]) << 16);

            unsigned s0 = __shfl_xor(u[0], 32), s1 = __shfl_xor(u[1], 32);
            unsigned s2 = __shfl_xor(u[2], 32), s3 = __shfl_xor(u[3], 32);
            unsigned s4 = __shfl_xor(u[4], 32), s5 = __shfl_xor(u[5], 32);
            unsigned s6 = __shfl_xor(u[6], 32), s7 = __shfl_xor(u[7], 32);
            PFrag pf0, pf1;
            pf0.w[0] = hi ? s2 : u[0];  pf0.w[1] = hi ? s3 : u[1];
            pf0.w[2] = hi ? u[2] : s0;  pf0.w[3] = hi ? u[3] : s1;
            pf1.w[0] = hi ? s6 : u[4];  pf1.w[1] = hi ? s7 : u[5];
            pf1.w[2] = hi ? u[6] : s4;  pf1.w[3] = hi ? u[7] : s5;

#pragma unroll
            for (int dt = 0; dt < 2; ++dt) {
                int drow = dt * 32 + lo5;
                int c0 = ((sub * 4) + 0 + hi) ^ (drow & 7);
                int c1 = ((sub * 4) + 2 + hi) ^ (drow & 7);
                bf16x8 vf0 = *(const bf16x8*)(Vt + drow * 64 + (c0 << 3));
                bf16x8 vf1 = *(const bf16x8*)(Vt + drow * 64 + (c1 << 3));
                f32x16& od = dt ? o1 : o0;
                od = __builtin_amdgcn_mfma_f32_32x32x16_bf16(vf0, pf0.v, od, 0, 0, 0);
                od = __builtin_amdgcn_mfma_f32_32x32x16_bf16(vf1, pf1.v, od, 0, 0, 0);
            }
        }
    }

    float* orow = Oh + (size_t)qg * DD;
#pragma unroll
    for (int dt = 0; dt < 2; ++dt) {
        const f32x16& od = dt ? o1 : o0;
#pragma unroll
        for (int g = 0; g < 4; ++g) {
            f32x4 st = { od[4*g+0] * rinv, od[4*g+1] * rinv, od[4*g+2] * rinv, od[4*g+3] * rinv };
            *(f32x4*)(orow + dt * 32 + g * 8 + hi * 4) = st;
        }
    }
}

extern "C" void kernel_launch(void* const* d_in, const int* in_sizes, int n_in,
                              void* d_out, int out_size, void* d_ws, size_t ws_size,
                              hipStream_t stream) {
    const float* Q = (const float*)d_in[0];
    const float* K = (const float*)d_in[1];
    const float* V = (const float*)d_in[2];
    float* O = (float*)d_out;
    float* P = O + (size_t)2 * 16 * SS * DD;

    const size_t HD = (size_t)32 * SS * DD;           // elems per tensor
    const size_t need = 3 * HD * sizeof(ushort_t);    // ~25.2 MB
    const float SCALE = 0.125f * 1.44269504088896340736f;

    if (ws_size >= need) {
        ushort_t* wsp  = (ushort_t*)d_ws;
        ushort_t* Qbf  = wsp;
        ushort_t* Kbf  = wsp + HD;
        ushort_t* Vtbf = wsp + 2 * HD;
        int n8 = (int)(HD / 8);
        hipLaunchKernelGGL(cvt_bf16, dim3(n8 / 256), dim3(256), 0, stream, Q, Qbf, n8, SCALE);
        hipLaunchKernelGGL(cvt_bf16, dim3(n8 / 256), dim3(256), 0, stream, K, Kbf, n8, 1.0f);
        hipLaunchKernelGGL(transposeV, dim3(1024), dim3(256), 0, stream, V, Vtbf);
        hipLaunchKernelGGL(attn_main, dim3(512), dim3(256), 0, stream, Qbf, Kbf, Vtbf, O, P);
    } else {
        hipLaunchKernelGGL(attn_fused, dim3(512), dim3(256), 0, stream, Q, K, V, O, P);
    }
}